// Round 6
// baseline (100.547 us; speedup 1.0000x reference)
//
#include <hip/hip_runtime.h>
#include <hip/hip_bf16.h>

#define BCH 32   // B*C heads
#define NN  2048
#define DD  64   // F = H = O

typedef __attribute__((ext_vector_type(8)))  __bf16 bf16x8;
typedef __attribute__((ext_vector_type(4)))  __bf16 bf16x4;
typedef __attribute__((ext_vector_type(4)))  float  f32x4;
typedef __attribute__((ext_vector_type(16))) float  f32x16;
typedef __attribute__((ext_vector_type(2)))  int    i32x2;
typedef __attribute__((ext_vector_type(4)))  int    i32x4;

__device__ inline f32x4 mfma16(bf16x8 a, bf16x8 b, f32x4 c) {
    return __builtin_amdgcn_mfma_f32_16x16x32_bf16(a, b, c, 0, 0, 0);
}
__device__ inline f32x16 mfma32(bf16x8 a, bf16x8 b, f32x16 c) {
    return __builtin_amdgcn_mfma_f32_32x32x16_bf16(a, b, c, 0, 0, 0);
}
__device__ inline void gload16(const void* g, void* l) {
    __builtin_amdgcn_global_load_lds(
        (const __attribute__((address_space(1))) void*)g,
        (__attribute__((address_space(3))) void*)l, 16, 0, 0);
}
// v_permlane32_swap_b32 vdst(a), vsrc(b): swaps a's HIGH lanes with b's LOW
// lanes (HK-pattern semantics, derived from m214 v22):
//   a_new = {own a on lanes<32, lo-partner's b on lanes>=32}
//   b_new = {hi-partner's a on lanes<32, own b on lanes>=32}
__device__ inline void plswap(int& a, int& b) {
    asm("v_permlane32_swap_b32 %0, %1" : "+v"(a), "+v"(b));
}

// ---------------------------------------------------------------------------
// Kernel 1: e1 = bf16(x@W1^T + b1), e2 = bf16(x@W2^T + b2)  [bc][n][h]
//           vT = bf16(x@W3^T)^T                              [bc][o][n]
// grid 1024 (32 heads * 32 strips of 64 n), block 256 = 4 waves.
// Wave w owns h/o block [w*16, w*16+16) for ALL 64 strip rows.
// e1/e2 via D[h][n] (A=W): lane holds 4 consecutive h -> packed bf16x4 store.
// vT  via D[n][o] (A=x): lane holds 4 consecutive n -> packed bf16x4 store.
// ---------------------------------------------------------------------------
__global__ __launch_bounds__(256) void prep_kernel(
    const float* __restrict__ x,
    const float* __restrict__ W1, const float* __restrict__ b1,
    const float* __restrict__ W2, const float* __restrict__ b2,
    const float* __restrict__ W3,
    __bf16* __restrict__ e1, __bf16* __restrict__ e2, __bf16* __restrict__ vT)
{
    const int t   = threadIdx.x;
    const int blk = blockIdx.x;
    const int bc  = blk >> 5, st = blk & 31;
    const long grow = (long)bc * NN + st * 64;
    const int w = t >> 6, l = t & 63, lg = l >> 4, li = l & 15;

    // x fragments: row = strip row nb*16+li, k = kk*32 + lg*8 + j
    bf16x8 a[4][2];
    #pragma unroll
    for (int nb = 0; nb < 4; ++nb)
        #pragma unroll
        for (int kk = 0; kk < 2; ++kk) {
            const float* p = x + (grow + nb * 16 + li) * DD + kk * 32 + lg * 8;
            f32x4 v0 = *(const f32x4*)p, v1 = *(const f32x4*)(p + 4);
            #pragma unroll
            for (int j = 0; j < 4; ++j) {
                a[nb][kk][j]     = (__bf16)v0[j];
                a[nb][kk][4 + j] = (__bf16)v1[j];
            }
        }

    // weight fragments for this wave's h-block: W[(w*16+li)][k]
    bf16x8 wf1[2], wf2[2], wf3[2];
    #pragma unroll
    for (int kk = 0; kk < 2; ++kk) {
        const float* p1 = W1 + (w * 16 + li) * DD + kk * 32 + lg * 8;
        const float* p2 = W2 + (w * 16 + li) * DD + kk * 32 + lg * 8;
        const float* p3 = W3 + (w * 16 + li) * DD + kk * 32 + lg * 8;
        f32x4 u0 = *(const f32x4*)p1, u1 = *(const f32x4*)(p1 + 4);
        f32x4 v0 = *(const f32x4*)p2, v1 = *(const f32x4*)(p2 + 4);
        f32x4 t0 = *(const f32x4*)p3, t1 = *(const f32x4*)(p3 + 4);
        #pragma unroll
        for (int j = 0; j < 4; ++j) {
            wf1[kk][j] = (__bf16)u0[j]; wf1[kk][4 + j] = (__bf16)u1[j];
            wf2[kk][j] = (__bf16)v0[j]; wf2[kk][4 + j] = (__bf16)v1[j];
            wf3[kk][j] = (__bf16)t0[j]; wf3[kk][4 + j] = (__bf16)t1[j];
        }
    }
    const f32x4 bq1 = *(const f32x4*)(b1 + w * 16 + lg * 4);
    const f32x4 bq2 = *(const f32x4*)(b2 + w * 16 + lg * 4);

    #pragma unroll
    for (int nb = 0; nb < 4; ++nb) {
        f32x4 acc1 = {0.f,0.f,0.f,0.f}, acc2 = {0.f,0.f,0.f,0.f}, acc3 = {0.f,0.f,0.f,0.f};
        #pragma unroll
        for (int kk = 0; kk < 2; ++kk) {
            acc1 = mfma16(wf1[kk], a[nb][kk], acc1);   // D[h][n]
            acc2 = mfma16(wf2[kk], a[nb][kk], acc2);   // D[h][n]
            acc3 = mfma16(a[nb][kk], wf3[kk], acc3);   // D[n][o]
        }
        bf16x4 q1, q2, q3;
        #pragma unroll
        for (int r = 0; r < 4; ++r) {
            q1[r] = (__bf16)(acc1[r] + bq1[r]);
            q2[r] = (__bf16)(acc2[r] + bq2[r]);
            q3[r] = (__bf16)acc3[r];
        }
        // e1/e2: n = grow+nb*16+li, h = w*16+lg*4 .. +3
        *(bf16x4*)&e1[(grow + nb * 16 + li) * DD + w * 16 + lg * 4] = q1;
        *(bf16x4*)&e2[(grow + nb * 16 + li) * DD + w * 16 + lg * 4] = q2;
        // vT: o = w*16+li, n = st*64 + nb*16 + lg*4 .. +3
        *(bf16x4*)&vT[((long)bc * DD + w * 16 + li) * NN + st * 64 + nb * 16 + lg * 4] = q3;
    }
}

// ---------------------------------------------------------------------------
// Kernel 2: out = relu(e1 e2^T) v + b3, flash-style, P never touches LDS.
// grid 512 (XCD-grouped: 16 nt x 32 bc), block 128 = 2 waves; wave owns 64 n.
// 32x32x16 MFMA; S^T = e2*e1^T (lane holds col n=l31); relu+pack+permlane32
// builds PV A-fragments in-register. e2/vT K-tiles staged via global_load_lds
// (pre-swizzled source, XOR 16B-slot), double-buffered, 2-phase.
// ---------------------------------------------------------------------------
__global__ __launch_bounds__(128) void fused_kernel(
    const __bf16* __restrict__ e1, const __bf16* __restrict__ e2,
    const __bf16* __restrict__ vT, const float* __restrict__ b3,
    float* __restrict__ out)
{
    __shared__ __bf16 e2t[2][64 * 64];   // [m][h], swizzled 16B slots
    __shared__ __bf16 vTt[2][64 * 64];   // [o][m], swizzled 16B slots

    const int t   = threadIdx.x;
    const int bid = blockIdx.x;
    // XCD grouping: bid%8 = XCD; each XCD owns 4 whole heads (2MB e2+vT in L2)
    const int x8 = bid & 7, jj = bid >> 3;
    const int bc = x8 * 4 + (jj >> 4), nt = jj & 15;

    const int w = t >> 6, l = t & 63;
    const int l31 = l & 31, hi5 = l >> 5, l7 = l & 7, l3 = l >> 3;
    const int nwave = nt * 128 + w * 64;

    // resident e1 B-fragments: n = nwave + nb*32 + l31, k = kk*16 + hi5*8
    bf16x8 e1f[2][4];
    #pragma unroll
    for (int nb = 0; nb < 2; ++nb) {
        const __bf16* p = e1 + ((size_t)bc * NN + nwave + nb * 32 + l31) * DD;
        #pragma unroll
        for (int kk = 0; kk < 4; ++kk)
            e1f[nb][kk] = *(const bf16x8*)(p + kk * 16 + hi5 * 8);
    }

    f32x16 hacc[2][2];
    #pragma unroll
    for (int nb = 0; nb < 2; ++nb)
        #pragma unroll
        for (int fb = 0; fb < 2; ++fb)
            #pragma unroll
            for (int i = 0; i < 16; ++i) hacc[nb][fb][i] = 0.f;

    const __bf16* e2h = e2 + (size_t)bc * NN * DD;
    const __bf16* vTh = vT + (size_t)bc * DD * NN;

    // stage K-tile kt: 8 chunks of 1KB per array; wave w does chunks w*4..w*4+3.
    // lane l -> row ch*8+l3, phys slot l7, global slot l7^l3 (= l7^(row&7)).
    auto stage = [&](int buf, int kt) {
        #pragma unroll
        for (int ii = 0; ii < 4; ++ii) {
            const int ch  = w * 4 + ii;
            const int row = ch * 8 + l3;
            const int q   = l7 ^ l3;
            gload16(e2h + ((size_t)(kt * 64 + row)) * DD + q * 8, &e2t[buf][ch * 512]);
            gload16(vTh + ((size_t)row) * NN + kt * 64 + q * 8, &vTt[buf][ch * 512]);
        }
    };

    stage(0, 0);
    __syncthreads();

    for (int kt = 0; kt < 32; ++kt) {
        const int buf = kt & 1;
        if (kt + 1 < 32) stage(buf ^ 1, kt + 1);

        // ---- S^T phase: s[nb] per mb; relu+pack quads to Q (dword pairs) ----
        // lane: col n = nb*32+l31; quad g holds m_local = 8g + 4*hi5 + 0..3
        i32x2 Q[2][2][4];   // [nb][mb][g]
        #pragma unroll
        for (int mb = 0; mb < 2; ++mb) {
            f32x16 s0, s1;
            #pragma unroll
            for (int i = 0; i < 16; ++i) { s0[i] = 0.f; s1[i] = 0.f; }
            #pragma unroll
            for (int kk = 0; kk < 4; ++kk) {
                const int slot = ((kk * 2 + hi5) ^ l7) * 8;
                bf16x8 ef = *(const bf16x8*)&e2t[buf][(mb * 32 + l31) * 64 + slot];
                s0 = mfma32(ef, e1f[0][kk], s0);
                s1 = mfma32(ef, e1f[1][kk], s1);
            }
            #pragma unroll
            for (int g = 0; g < 4; ++g) {
                bf16x4 q0, q1;
                #pragma unroll
                for (int r = 0; r < 4; ++r) {
                    float v0 = s0[4 * g + r], v1 = s1[4 * g + r];
                    q0[r] = (__bf16)(v0 > 0.f ? v0 : 0.f);
                    q1[r] = (__bf16)(v1 > 0.f ? v1 : 0.f);
                }
                Q[0][mb][g] = __builtin_bit_cast(i32x2, q0);
                Q[1][mb][g] = __builtin_bit_cast(i32x2, q1);
            }
        }

        // ---- PV phase: pf built via permlane32_swap (no LDS for P) ----
        // HK pattern: plswap(qA=low 8-group quad, qB=high 8-group quad)
        //   -> qA = pf dwords j{0,1}/{2,3}, qB = pf dwords j{4,5}/{6,7}
        // giving pf[j] = P[n][16*kk2 + 8*hi5 + j] on every lane.
        #pragma unroll
        for (int kk2 = 0; kk2 < 4; ++kk2) {
            const int mb = kk2 >> 1, c = kk2 & 1;
            const int slot = ((kk2 * 2 + hi5) ^ l7) * 8;
            bf16x8 vf0 = *(const bf16x8*)&vTt[buf][(l31) * 64 + slot];
            bf16x8 vf1 = *(const bf16x8*)&vTt[buf][(32 + l31) * 64 + slot];
            #pragma unroll
            for (int nb = 0; nb < 2; ++nb) {
                int a0 = Q[nb][mb][2 * c][0],     a1 = Q[nb][mb][2 * c][1];     // qA
                int b0 = Q[nb][mb][2 * c + 1][0], b1 = Q[nb][mb][2 * c + 1][1]; // qB
                plswap(a0, b0);
                plswap(a1, b1);
                i32x4 pfi = { a0, a1, b0, b1 };
                bf16x8 pf = __builtin_bit_cast(bf16x8, pfi);
                hacc[nb][0] = mfma32(pf, vf0, hacc[nb][0]);
                hacc[nb][1] = mfma32(pf, vf1, hacc[nb][1]);
            }
        }

        __syncthreads();   // drains staging vmcnt; all reads of buf done
    }

    // epilogue: out = hacc + b3 (fp32). row n = (reg&3)+8*(reg>>2)+4*hi5
    const float bv0 = b3[l31], bv1 = b3[32 + l31];
    #pragma unroll
    for (int nb = 0; nb < 2; ++nb) {
        const size_t ob = ((size_t)bc * NN + nwave + nb * 32) * DD;
        #pragma unroll
        for (int reg = 0; reg < 16; ++reg) {
            const int n = (reg & 3) + 8 * (reg >> 2) + 4 * hi5;
            out[ob + (size_t)n * DD + l31]      = hacc[nb][0][reg] + bv0;
            out[ob + (size_t)n * DD + 32 + l31] = hacc[nb][1][reg] + bv1;
        }
    }
}

extern "C" void kernel_launch(void* const* d_in, const int* in_sizes, int n_in,
                              void* d_out, int out_size, void* d_ws, size_t ws_size,
                              hipStream_t stream) {
    const float* x  = (const float*)d_in[0];
    const float* W1 = (const float*)d_in[1];
    const float* b1 = (const float*)d_in[2];
    const float* W2 = (const float*)d_in[3];
    const float* b2 = (const float*)d_in[4];
    const float* W3 = (const float*)d_in[5];
    const float* b3 = (const float*)d_in[6];
    float* out = (float*)d_out;

    __bf16* e1 = (__bf16*)d_ws;                       // 8 MB
    __bf16* e2 = e1 + (size_t)BCH * NN * DD;          // 8 MB
    __bf16* vT = e2 + (size_t)BCH * NN * DD;          // 8 MB

    prep_kernel<<<dim3(1024), dim3(256), 0, stream>>>(x, W1, b1, W2, b2, W3, e1, e2, vT);
    fused_kernel<<<dim3(512), dim3(128), 0, stream>>>(e1, e2, vT, b3, out);
}

// Round 9
// 76.390 us; speedup vs baseline: 1.3162x; 1.3162x over previous
//
#include <hip/hip_runtime.h>
#include <hip/hip_bf16.h>

#define BCH 32   // B*C heads
#define NN  2048
#define DD  64   // F = H = O

typedef __attribute__((ext_vector_type(8)))  __bf16 bf16x8;
typedef __attribute__((ext_vector_type(4)))  __bf16 bf16x4;
typedef __attribute__((ext_vector_type(4)))  float  f32x4;
typedef __attribute__((ext_vector_type(16))) float  f32x16;
typedef __attribute__((ext_vector_type(2)))  int    i32x2;
typedef __attribute__((ext_vector_type(4)))  int    i32x4;
typedef __attribute__((ext_vector_type(2)))  unsigned int u32x2;

__device__ inline f32x4 mfma16(bf16x8 a, bf16x8 b, f32x4 c) {
    return __builtin_amdgcn_mfma_f32_16x16x32_bf16(a, b, c, 0, 0, 0);
}
__device__ inline f32x16 mfma32(bf16x8 a, bf16x8 b, f32x16 c) {
    return __builtin_amdgcn_mfma_f32_32x32x16_bf16(a, b, c, 0, 0, 0);
}
__device__ inline void gload16(const void* g, void* l) {
    __builtin_amdgcn_global_load_lds(
        (const __attribute__((address_space(1))) void*)g,
        (__attribute__((address_space(3))) void*)l, 16, 0, 0);
}
// permlane32_swap via BUILTIN (compiler-modeled -> hazard waits inserted).
// Semantics (validated round 6): exchanges a's high 32 lanes with b's low 32:
//   a_new = {own a on lanes<32, b[lane-32] on lanes>=32}
//   b_new = {a[lane+32] on lanes<32, own b on lanes>=32}
__device__ inline void plswap(int& a, int& b) {
    u32x2 r = __builtin_amdgcn_permlane32_swap((unsigned)a, (unsigned)b, false, false);
    a = (int)r[0];
    b = (int)r[1];
}

// ---------------------------------------------------------------------------
// Kernel 1 (unchanged, validated rounds 6-7): e1/e2 [bc][n][h], vT [bc][o][n]
// ---------------------------------------------------------------------------
__global__ __launch_bounds__(256) void prep_kernel(
    const float* __restrict__ x,
    const float* __restrict__ W1, const float* __restrict__ b1,
    const float* __restrict__ W2, const float* __restrict__ b2,
    const float* __restrict__ W3,
    __bf16* __restrict__ e1, __bf16* __restrict__ e2, __bf16* __restrict__ vT)
{
    const int t   = threadIdx.x;
    const int blk = blockIdx.x;
    const int bc  = blk >> 5, st = blk & 31;
    const long grow = (long)bc * NN + st * 64;
    const int w = t >> 6, l = t & 63, lg = l >> 4, li = l & 15;

    bf16x8 a[4][2];
    #pragma unroll
    for (int nb = 0; nb < 4; ++nb)
        #pragma unroll
        for (int kk = 0; kk < 2; ++kk) {
            const float* p = x + (grow + nb * 16 + li) * DD + kk * 32 + lg * 8;
            f32x4 v0 = *(const f32x4*)p, v1 = *(const f32x4*)(p + 4);
            #pragma unroll
            for (int j = 0; j < 4; ++j) {
                a[nb][kk][j]     = (__bf16)v0[j];
                a[nb][kk][4 + j] = (__bf16)v1[j];
            }
        }

    bf16x8 wf1[2], wf2[2], wf3[2];
    #pragma unroll
    for (int kk = 0; kk < 2; ++kk) {
        const float* p1 = W1 + (w * 16 + li) * DD + kk * 32 + lg * 8;
        const float* p2 = W2 + (w * 16 + li) * DD + kk * 32 + lg * 8;
        const float* p3 = W3 + (w * 16 + li) * DD + kk * 32 + lg * 8;
        f32x4 u0 = *(const f32x4*)p1, u1 = *(const f32x4*)(p1 + 4);
        f32x4 v0 = *(const f32x4*)p2, v1 = *(const f32x4*)(p2 + 4);
        f32x4 t0 = *(const f32x4*)p3, t1 = *(const f32x4*)(p3 + 4);
        #pragma unroll
        for (int j = 0; j < 4; ++j) {
            wf1[kk][j] = (__bf16)u0[j]; wf1[kk][4 + j] = (__bf16)u1[j];
            wf2[kk][j] = (__bf16)v0[j]; wf2[kk][4 + j] = (__bf16)v1[j];
            wf3[kk][j] = (__bf16)t0[j]; wf3[kk][4 + j] = (__bf16)t1[j];
        }
    }
    const f32x4 bq1 = *(const f32x4*)(b1 + w * 16 + lg * 4);
    const f32x4 bq2 = *(const f32x4*)(b2 + w * 16 + lg * 4);

    #pragma unroll
    for (int nb = 0; nb < 4; ++nb) {
        f32x4 acc1 = {0.f,0.f,0.f,0.f}, acc2 = {0.f,0.f,0.f,0.f}, acc3 = {0.f,0.f,0.f,0.f};
        #pragma unroll
        for (int kk = 0; kk < 2; ++kk) {
            acc1 = mfma16(wf1[kk], a[nb][kk], acc1);   // D[h][n]
            acc2 = mfma16(wf2[kk], a[nb][kk], acc2);   // D[h][n]
            acc3 = mfma16(a[nb][kk], wf3[kk], acc3);   // D[n][o]
        }
        bf16x4 q1, q2, q3;
        #pragma unroll
        for (int r = 0; r < 4; ++r) {
            q1[r] = (__bf16)(acc1[r] + bq1[r]);
            q2[r] = (__bf16)(acc2[r] + bq2[r]);
            q3[r] = (__bf16)acc3[r];
        }
        *(bf16x4*)&e1[(grow + nb * 16 + li) * DD + w * 16 + lg * 4] = q1;
        *(bf16x4*)&e2[(grow + nb * 16 + li) * DD + w * 16 + lg * 4] = q2;
        *(bf16x4*)&vT[((long)bc * DD + w * 16 + li) * NN + st * 64 + nb * 16 + lg * 4] = q3;
    }
}

// ---------------------------------------------------------------------------
// Kernel 2: out = relu(e1 e2^T) v + b3. P never touches LDS (permlane32).
// grid 1024 (XCD-grouped: 32 nt x 32 bc), block 128 = 2 waves; wave owns 32 n.
// -> 2048 waves = 2 waves/SIMD, 4 blocks/CU (4 independent barrier domains).
// 32x32x16 MFMA; S^T = e2*e1^T (lane holds col n=l31). e2/vT K-tiles staged
// via global_load_lds (pre-swizzled source, XOR 16B-slot), double-buffered.
// ---------------------------------------------------------------------------
__global__ __launch_bounds__(128) void fused_kernel(
    const __bf16* __restrict__ e1, const __bf16* __restrict__ e2,
    const __bf16* __restrict__ vT, const float* __restrict__ b3,
    float* __restrict__ out)
{
    __shared__ __bf16 e2t[2][64 * 64];   // [m][h], swizzled 16B slots
    __shared__ __bf16 vTt[2][64 * 64];   // [o][m], swizzled 16B slots

    const int t   = threadIdx.x;
    const int bid = blockIdx.x;
    // XCD grouping: bid%8 = XCD; each XCD owns 4 whole heads (2MB e2+vT in L2)
    const int x8 = bid & 7, jj = bid >> 3;          // jj in 0..127
    const int bc = x8 * 4 + (jj >> 5), nt = jj & 31;

    const int w = t >> 6, l = t & 63;
    const int l31 = l & 31, hi5 = l >> 5, l7 = l & 7, l3 = l >> 3;
    const int nwave = nt * 64 + w * 32;

    // resident e1 B-fragments: n = nwave + l31, k = kk*16 + hi5*8
    bf16x8 e1f[4];
    {
        const __bf16* p = e1 + ((size_t)bc * NN + nwave + l31) * DD;
        #pragma unroll
        for (int kk = 0; kk < 4; ++kk)
            e1f[kk] = *(const bf16x8*)(p + kk * 16 + hi5 * 8);
    }

    f32x16 hacc[2];
    #pragma unroll
    for (int fb = 0; fb < 2; ++fb)
        #pragma unroll
        for (int i = 0; i < 16; ++i) hacc[fb][i] = 0.f;

    const __bf16* e2h = e2 + (size_t)bc * NN * DD;
    const __bf16* vTh = vT + (size_t)bc * DD * NN;

    // stage K-tile kt: 8 chunks of 1KB per array; wave w does chunks w*4..w*4+3.
    // lane l -> row ch*8+l3, phys slot l7, global slot l7^l3 (= l7^(row&7)).
    auto stage = [&](int buf, int kt) {
        #pragma unroll
        for (int ii = 0; ii < 4; ++ii) {
            const int ch  = w * 4 + ii;
            const int row = ch * 8 + l3;
            const int q   = l7 ^ l3;
            gload16(e2h + ((size_t)(kt * 64 + row)) * DD + q * 8, &e2t[buf][ch * 512]);
            gload16(vTh + ((size_t)row) * NN + kt * 64 + q * 8, &vTt[buf][ch * 512]);
        }
    };

    stage(0, 0);
    __syncthreads();

    for (int kt = 0; kt < 32; ++kt) {
        const int buf = kt & 1;
        if (kt + 1 < 32) stage(buf ^ 1, kt + 1);

        // ---- S^T phase: relu+pack quads to Q (dword pairs) ----
        // lane: col n = l31; quad g holds m_local = mb*32 + 8g + 4*hi5 + 0..3
        i32x2 Q[2][4];   // [mb][g]
        #pragma unroll
        for (int mb = 0; mb < 2; ++mb) {
            f32x16 s;
            #pragma unroll
            for (int i = 0; i < 16; ++i) s[i] = 0.f;
            #pragma unroll
            for (int kk = 0; kk < 4; ++kk) {
                const int slot = ((kk * 2 + hi5) ^ l7) * 8;
                bf16x8 ef = *(const bf16x8*)&e2t[buf][(mb * 32 + l31) * 64 + slot];
                s = mfma32(ef, e1f[kk], s);
            }
            #pragma unroll
            for (int g = 0; g < 4; ++g) {
                bf16x4 q0;
                #pragma unroll
                for (int r = 0; r < 4; ++r) {
                    float v = s[4 * g + r];
                    q0[r] = (__bf16)(v > 0.f ? v : 0.f);
                }
                Q[mb][g] = __builtin_bit_cast(i32x2, q0);
            }
        }

        // ---- PV phase: pf built via permlane32_swap builtin ----
        // pf[j] = P[n=own l31][m = 16*kk2 + 8*hi5 + j]
        #pragma unroll
        for (int kk2 = 0; kk2 < 4; ++kk2) {
            const int mb = kk2 >> 1, c = kk2 & 1;
            const int slot = ((kk2 * 2 + hi5) ^ l7) * 8;
            bf16x8 vf0 = *(const bf16x8*)&vTt[buf][(l31) * 64 + slot];
            bf16x8 vf1 = *(const bf16x8*)&vTt[buf][(32 + l31) * 64 + slot];
            int a0 = Q[mb][2 * c][0],     a1 = Q[mb][2 * c][1];     // qA
            int b0 = Q[mb][2 * c + 1][0], b1 = Q[mb][2 * c + 1][1]; // qB
            plswap(a0, b0);
            plswap(a1, b1);
            i32x4 pfi = { a0, a1, b0, b1 };
            bf16x8 pf = __builtin_bit_cast(bf16x8, pfi);
            hacc[0] = mfma32(pf, vf0, hacc[0]);
            hacc[1] = mfma32(pf, vf1, hacc[1]);
        }

        __syncthreads();   // drains staging vmcnt; all reads of buf done
    }

    // epilogue: out = hacc + b3 (fp32). row n = (reg&3)+8*(reg>>2)+4*hi5
    const float bv0 = b3[l31], bv1 = b3[32 + l31];
    const size_t ob = ((size_t)bc * NN + nwave) * DD;
    #pragma unroll
    for (int reg = 0; reg < 16; ++reg) {
        const int n = (reg & 3) + 8 * (reg >> 2) + 4 * hi5;
        out[ob + (size_t)n * DD + l31]      = hacc[0][reg] + bv0;
        out[ob + (size_t)n * DD + 32 + l31] = hacc[1][reg] + bv1;
    }
}

extern "C" void kernel_launch(void* const* d_in, const int* in_sizes, int n_in,
                              void* d_out, int out_size, void* d_ws, size_t ws_size,
                              hipStream_t stream) {
    const float* x  = (const float*)d_in[0];
    const float* W1 = (const float*)d_in[1];
    const float* b1 = (const float*)d_in[2];
    const float* W2 = (const float*)d_in[3];
    const float* b2 = (const float*)d_in[4];
    const float* W3 = (const float*)d_in[5];
    const float* b3 = (const float*)d_in[6];
    float* out = (float*)d_out;

    __bf16* e1 = (__bf16*)d_ws;                       // 8 MB
    __bf16* e2 = e1 + (size_t)BCH * NN * DD;          // 8 MB
    __bf16* vT = e2 + (size_t)BCH * NN * DD;          // 8 MB

    prep_kernel<<<dim3(1024), dim3(256), 0, stream>>>(x, W1, b1, W2, b2, W3, e1, e2, vT);
    fused_kernel<<<dim3(1024), dim3(128), 0, stream>>>(e1, e2, vT, b3, out);
}

// Round 10
// 68.078 us; speedup vs baseline: 1.4769x; 1.1221x over previous
//
#include <hip/hip_runtime.h>
#include <hip/hip_bf16.h>

#define BCH 32   // B*C heads
#define NN  2048
#define DD  64   // F = H = O

typedef __attribute__((ext_vector_type(8)))  __bf16 bf16x8;
typedef __attribute__((ext_vector_type(4)))  __bf16 bf16x4;
typedef __attribute__((ext_vector_type(4)))  float  f32x4;
typedef __attribute__((ext_vector_type(16))) float  f32x16;
typedef __attribute__((ext_vector_type(2)))  int    i32x2;
typedef __attribute__((ext_vector_type(4)))  int    i32x4;
typedef __attribute__((ext_vector_type(2)))  unsigned int u32x2;

__device__ inline f32x4 mfma16(bf16x8 a, bf16x8 b, f32x4 c) {
    return __builtin_amdgcn_mfma_f32_16x16x32_bf16(a, b, c, 0, 0, 0);
}
__device__ inline f32x16 mfma32(bf16x8 a, bf16x8 b, f32x16 c) {
    return __builtin_amdgcn_mfma_f32_32x32x16_bf16(a, b, c, 0, 0, 0);
}
__device__ inline void gload16(const void* g, void* l) {
    __builtin_amdgcn_global_load_lds(
        (const __attribute__((address_space(1))) void*)g,
        (__attribute__((address_space(3))) void*)l, 16, 0, 0);
}
// permlane32_swap BUILTIN (validated round 9; inline-asm version caused
// nondeterministic corruption -> MFMA-operand hazard not inserted).
__device__ inline void plswap(int& a, int& b) {
    u32x2 r = __builtin_amdgcn_permlane32_swap((unsigned)a, (unsigned)b, false, false);
    a = (int)r[0];
    b = (int)r[1];
}

// ---------------------------------------------------------------------------
// Kernel 1 (unchanged, validated rounds 6-9): e1/e2 [bc][n][h], vT [bc][o][n]
// ---------------------------------------------------------------------------
__global__ __launch_bounds__(256) void prep_kernel(
    const float* __restrict__ x,
    const float* __restrict__ W1, const float* __restrict__ b1,
    const float* __restrict__ W2, const float* __restrict__ b2,
    const float* __restrict__ W3,
    __bf16* __restrict__ e1, __bf16* __restrict__ e2, __bf16* __restrict__ vT)
{
    const int t   = threadIdx.x;
    const int blk = blockIdx.x;
    const int bc  = blk >> 5, st = blk & 31;
    const long grow = (long)bc * NN + st * 64;
    const int w = t >> 6, l = t & 63, lg = l >> 4, li = l & 15;

    bf16x8 a[4][2];
    #pragma unroll
    for (int nb = 0; nb < 4; ++nb)
        #pragma unroll
        for (int kk = 0; kk < 2; ++kk) {
            const float* p = x + (grow + nb * 16 + li) * DD + kk * 32 + lg * 8;
            f32x4 v0 = *(const f32x4*)p, v1 = *(const f32x4*)(p + 4);
            #pragma unroll
            for (int j = 0; j < 4; ++j) {
                a[nb][kk][j]     = (__bf16)v0[j];
                a[nb][kk][4 + j] = (__bf16)v1[j];
            }
        }

    bf16x8 wf1[2], wf2[2], wf3[2];
    #pragma unroll
    for (int kk = 0; kk < 2; ++kk) {
        const float* p1 = W1 + (w * 16 + li) * DD + kk * 32 + lg * 8;
        const float* p2 = W2 + (w * 16 + li) * DD + kk * 32 + lg * 8;
        const float* p3 = W3 + (w * 16 + li) * DD + kk * 32 + lg * 8;
        f32x4 u0 = *(const f32x4*)p1, u1 = *(const f32x4*)(p1 + 4);
        f32x4 v0 = *(const f32x4*)p2, v1 = *(const f32x4*)(p2 + 4);
        f32x4 t0 = *(const f32x4*)p3, t1 = *(const f32x4*)(p3 + 4);
        #pragma unroll
        for (int j = 0; j < 4; ++j) {
            wf1[kk][j] = (__bf16)u0[j]; wf1[kk][4 + j] = (__bf16)u1[j];
            wf2[kk][j] = (__bf16)v0[j]; wf2[kk][4 + j] = (__bf16)v1[j];
            wf3[kk][j] = (__bf16)t0[j]; wf3[kk][4 + j] = (__bf16)t1[j];
        }
    }
    const f32x4 bq1 = *(const f32x4*)(b1 + w * 16 + lg * 4);
    const f32x4 bq2 = *(const f32x4*)(b2 + w * 16 + lg * 4);

    #pragma unroll
    for (int nb = 0; nb < 4; ++nb) {
        f32x4 acc1 = {0.f,0.f,0.f,0.f}, acc2 = {0.f,0.f,0.f,0.f}, acc3 = {0.f,0.f,0.f,0.f};
        #pragma unroll
        for (int kk = 0; kk < 2; ++kk) {
            acc1 = mfma16(wf1[kk], a[nb][kk], acc1);   // D[h][n]
            acc2 = mfma16(wf2[kk], a[nb][kk], acc2);   // D[h][n]
            acc3 = mfma16(a[nb][kk], wf3[kk], acc3);   // D[n][o]
        }
        bf16x4 q1, q2, q3;
        #pragma unroll
        for (int r = 0; r < 4; ++r) {
            q1[r] = (__bf16)(acc1[r] + bq1[r]);
            q2[r] = (__bf16)(acc2[r] + bq2[r]);
            q3[r] = (__bf16)acc3[r];
        }
        *(bf16x4*)&e1[(grow + nb * 16 + li) * DD + w * 16 + lg * 4] = q1;
        *(bf16x4*)&e2[(grow + nb * 16 + li) * DD + w * 16 + lg * 4] = q2;
        *(bf16x4*)&vT[((long)bc * DD + w * 16 + li) * NN + st * 64 + nb * 16 + lg * 4] = q3;
    }
}

// ---------------------------------------------------------------------------
// Kernel 2: out = relu(e1 e2^T) v + b3. m-split flash:
// grid 512 (XCD-grouped: 16 nt x 32 bc), block 256 = 4 waves = 2 n-waves x
// 2 m-waves. Wave (wm,wn): 64 n (2 nb) x its 32-m half of each 64-m K-tile.
// Each LDS fragment read feeds 2 MFMAs. Partial hacc combined across wm at
// epilogue via LDS. Counted vmcnt(4) + raw barriers (no per-kt drain).
// ---------------------------------------------------------------------------
__global__ __launch_bounds__(256) void fused_kernel(
    const __bf16* __restrict__ e1, const __bf16* __restrict__ e2,
    const __bf16* __restrict__ vT, const float* __restrict__ b3,
    float* __restrict__ out)
{
    __shared__ __align__(16) unsigned char smem[32768];
    __bf16* e2t = (__bf16*)smem;             // [2][4096] bf16: [m][h] swizzled
    __bf16* vTt = (__bf16*)(smem + 16384);   // [2][4096] bf16: [o][m] swizzled
    float*  scratch = (float*)smem;          // epilogue reuse (32KB)

    const int t   = threadIdx.x;
    const int bid = blockIdx.x;
    const int x8 = bid & 7, jj = bid >> 3;          // jj in 0..63
    const int bc = x8 * 4 + (jj >> 4), nt = jj & 15;

    const int w = t >> 6, l = t & 63;
    const int wn = w & 1, wm = w >> 1;
    const int l31 = l & 31, hi5 = l >> 5, l7 = l & 7, l3 = l >> 3;
    const int nbase = nt * 128 + wn * 64;

    // resident e1 B-fragments: n = nbase + nb*32 + l31, k = kk*16 + hi5*8
    bf16x8 e1f[2][4];
    #pragma unroll
    for (int nb = 0; nb < 2; ++nb) {
        const __bf16* p = e1 + ((size_t)bc * NN + nbase + nb * 32 + l31) * DD;
        #pragma unroll
        for (int kk = 0; kk < 4; ++kk)
            e1f[nb][kk] = *(const bf16x8*)(p + kk * 16 + hi5 * 8);
    }

    f32x16 hacc[2][2];   // [nb][fb], partial over this wave's m-half
    #pragma unroll
    for (int nb = 0; nb < 2; ++nb)
        #pragma unroll
        for (int fb = 0; fb < 2; ++fb)
            #pragma unroll
            for (int i = 0; i < 16; ++i) hacc[nb][fb][i] = 0.f;

    const __bf16* e2h = e2 + (size_t)bc * NN * DD;
    const __bf16* vTh = vT + (size_t)bc * DD * NN;

    // stage K-tile kt: 8 chunks of 1KB per array; wave w does chunks 2w,2w+1.
    // 4 gload16 per wave per stage. lane l -> row ch*8+l3, phys slot l7,
    // global slot l7^l3 (LDS slot s holds global slot s^(row&7)).
    auto stage = [&](int buf, int kt) {
        #pragma unroll
        for (int ii = 0; ii < 2; ++ii) {
            const int ch  = w * 2 + ii;
            const int row = ch * 8 + l3;
            const int q   = l7 ^ l3;
            gload16(e2h + ((size_t)(kt * 64 + row)) * DD + q * 8, &e2t[buf * 4096 + ch * 512]);
            gload16(vTh + ((size_t)row) * NN + kt * 64 + q * 8, &vTt[buf * 4096 + ch * 512]);
        }
    };

    stage(0, 0);

    for (int kt = 0; kt < 32; ++kt) {
        const int buf = kt & 1;
        if (kt + 1 < 32) {
            stage(buf ^ 1, kt + 1);
            asm volatile("s_waitcnt vmcnt(4)" ::: "memory");   // kt's 4 landed
        } else {
            asm volatile("s_waitcnt vmcnt(0)" ::: "memory");
        }
        __builtin_amdgcn_sched_barrier(0);
        __builtin_amdgcn_s_barrier();      // all waves have kt's tile

        // ---- S^T phase: rows m = wm*32 + l31's quad-range; cols n (lane) ----
        f32x16 s[2];
        #pragma unroll
        for (int nb = 0; nb < 2; ++nb)
            #pragma unroll
            for (int i = 0; i < 16; ++i) s[nb][i] = 0.f;
        __builtin_amdgcn_s_setprio(1);
        #pragma unroll
        for (int kk = 0; kk < 4; ++kk) {
            const int slot = ((kk * 2 + hi5) ^ l7) * 8;
            bf16x8 ef = *(const bf16x8*)&e2t[buf * 4096 + (wm * 32 + l31) * 64 + slot];
            s[0] = mfma32(ef, e1f[0][kk], s[0]);
            s[1] = mfma32(ef, e1f[1][kk], s[1]);
        }
        __builtin_amdgcn_s_setprio(0);

        // relu + pack quads: quad g holds m_local = 8g + 4*hi5 + 0..3
        i32x2 Q[2][4];
        #pragma unroll
        for (int nb = 0; nb < 2; ++nb)
            #pragma unroll
            for (int g = 0; g < 4; ++g) {
                bf16x4 q0;
                #pragma unroll
                for (int r = 0; r < 4; ++r) {
                    float v = s[nb][4 * g + r];
                    q0[r] = (__bf16)(v > 0.f ? v : 0.f);
                }
                Q[nb][g] = __builtin_bit_cast(i32x2, q0);
            }

        // ---- PV phase: pf[j] = P[n][m = wm*32 + 16*kk2 + 8*hi5 + j] ----
        __builtin_amdgcn_s_setprio(1);
        #pragma unroll
        for (int kk2 = 0; kk2 < 2; ++kk2) {
            const int slot = ((wm * 4 + kk2 * 2 + hi5) ^ l7) * 8;
            bf16x8 vf0 = *(const bf16x8*)&vTt[buf * 4096 + (l31) * 64 + slot];
            bf16x8 vf1 = *(const bf16x8*)&vTt[buf * 4096 + (32 + l31) * 64 + slot];
            #pragma unroll
            for (int nb = 0; nb < 2; ++nb) {
                int a0 = Q[nb][2 * kk2][0],     a1 = Q[nb][2 * kk2][1];
                int b0 = Q[nb][2 * kk2 + 1][0], b1 = Q[nb][2 * kk2 + 1][1];
                plswap(a0, b0);
                plswap(a1, b1);
                i32x4 pfi = { a0, a1, b0, b1 };
                bf16x8 pf = __builtin_bit_cast(bf16x8, pfi);
                hacc[nb][0] = mfma32(pf, vf0, hacc[nb][0]);
                hacc[nb][1] = mfma32(pf, vf1, hacc[nb][1]);
            }
        }
        __builtin_amdgcn_s_setprio(0);

        __builtin_amdgcn_s_barrier();      // all reads of buf done (next stage overwrites buf^1... safe: it was read at kt-1)
    }

    // ---- epilogue: combine m-halves, add b3, store fp32 ----
    if (wm == 1) {
        #pragma unroll
        for (int q = 0; q < 16; ++q) {
            f32x4 v;
            #pragma unroll
            for (int r = 0; r < 4; ++r) {
                const int idx = q * 4 + r;
                v[r] = hacc[idx >> 5][(idx >> 4) & 1][idx & 15];
            }
            *(f32x4*)&scratch[wn * 4096 + q * 256 + l * 4] = v;
        }
    }
    __syncthreads();
    if (wm == 0) {
        #pragma unroll
        for (int q = 0; q < 16; ++q) {
            f32x4 v = *(const f32x4*)&scratch[wn * 4096 + q * 256 + l * 4];
            #pragma unroll
            for (int r = 0; r < 4; ++r) {
                const int idx = q * 4 + r;
                hacc[idx >> 5][(idx >> 4) & 1][idx & 15] += v[r];
            }
        }
        const float bv0 = b3[l31], bv1 = b3[32 + l31];
        #pragma unroll
        for (int nb = 0; nb < 2; ++nb) {
            const size_t ob = ((size_t)bc * NN + nbase + nb * 32) * DD;
            #pragma unroll
            for (int reg = 0; reg < 16; ++reg) {
                const int n = (reg & 3) + 8 * (reg >> 2) + 4 * hi5;
                out[ob + (size_t)n * DD + l31]      = hacc[nb][0][reg] + bv0;
                out[ob + (size_t)n * DD + 32 + l31] = hacc[nb][1][reg] + bv1;
            }
        }
    }
}

extern "C" void kernel_launch(void* const* d_in, const int* in_sizes, int n_in,
                              void* d_out, int out_size, void* d_ws, size_t ws_size,
                              hipStream_t stream) {
    const float* x  = (const float*)d_in[0];
    const float* W1 = (const float*)d_in[1];
    const float* b1 = (const float*)d_in[2];
    const float* W2 = (const float*)d_in[3];
    const float* b2 = (const float*)d_in[4];
    const float* W3 = (const float*)d_in[5];
    const float* b3 = (const float*)d_in[6];
    float* out = (float*)d_out;

    __bf16* e1 = (__bf16*)d_ws;                       // 8 MB
    __bf16* e2 = e1 + (size_t)BCH * NN * DD;          // 8 MB
    __bf16* vT = e2 + (size_t)BCH * NN * DD;          // 8 MB

    prep_kernel<<<dim3(1024), dim3(256), 0, stream>>>(x, W1, b1, W2, b2, W3, e1, e2, vT);
    fused_kernel<<<dim3(512), dim3(256), 0, stream>>>(e1, e2, vT, b3, out);
}